// Round 3
// baseline (259.103 us; speedup 1.0000x reference)
//
#include <hip/hip_runtime.h>
#include <hip/hip_bf16.h>

// Swin shifted-window attention, fused, register-resident via MFMA layout chaining.
// B=64, H=W=56, DIM=128, 4 heads, WS=7. 1 block = 1 window (4096), wave = head.
// fp32 global I/O; bf16 16x16x32 MFMA internally; q-weights pre-scaled by SCALE*log2e.

#define NTOK 49
#define QS (0.08838834764831844f * 1.4426950408889634f)  // 128^-0.5 * log2(e)

typedef __bf16 bf16x8 __attribute__((ext_vector_type(8)));
typedef __bf16 bf16x2 __attribute__((ext_vector_type(2)));
typedef float  f32x4  __attribute__((ext_vector_type(4)));
typedef unsigned int u32x4 __attribute__((ext_vector_type(4)));

__device__ __forceinline__ f32x4 mfma_bf16(bf16x8 a, bf16x8 b, f32x4 c) {
  return __builtin_amdgcn_mfma_f32_16x16x32_bf16(a, b, c, 0, 0, 0);
}

__device__ __forceinline__ unsigned int pack2(float lo, float hi) {
  bf16x2 t; t[0] = (__bf16)lo; t[1] = (__bf16)hi;
  return __builtin_bit_cast(unsigned int, t);
}

__device__ __forceinline__ bf16x8 cvt8(f32x4 a, f32x4 b) {
  bf16x8 r;
#pragma unroll
  for (int j = 0; j < 4; ++j) { r[j] = (__bf16)a[j]; r[4 + j] = (__bf16)b[j]; }
  return r;
}

// C-tile (col=c, rows over lgrp*4+r in 2 row-tiles t0,t1) -> A/B-frag
// (idx=c, kelem = g*8+j over the 32 rows). Push-permute, 4 ds_permute + selects.
// Source lane sl pushes tile T word w to lane ((2T + (sl>>1))<<4)|c, landing in
// frag slot 2*(sl&1)+w. Op A uses T=sl&1, op B uses T=1-(sl&1): both bijective.
__device__ __forceinline__ bf16x8 push_frag(unsigned int t0w0, unsigned int t0w1,
                                            unsigned int t1w0, unsigned int t1w1,
                                            int addrA, int addrB, int g0, int g1) {
  unsigned int a0 = g0 ? t1w0 : t0w0;   // op A value (T = own g0)
  unsigned int a1 = g0 ? t1w1 : t0w1;
  unsigned int b0 = g0 ? t0w0 : t1w0;   // op B value (T = 1 - g0)
  unsigned int b1 = g0 ? t0w1 : t1w1;
  unsigned int rA0 = (unsigned int)__builtin_amdgcn_ds_permute(addrA, (int)a0);
  unsigned int rA1 = (unsigned int)__builtin_amdgcn_ds_permute(addrA, (int)a1);
  unsigned int rB0 = (unsigned int)__builtin_amdgcn_ds_permute(addrB, (int)b0);
  unsigned int rB1 = (unsigned int)__builtin_amdgcn_ds_permute(addrB, (int)b1);
  u32x4 u;
  u[0] = g1 ? rB0 : rA0;
  u[1] = g1 ? rB1 : rA1;
  u[2] = g1 ? rA0 : rB0;
  u[3] = g1 ? rA1 : rB1;
  return __builtin_bit_cast(bf16x8, u);
}

// region id for the shifted-window mask, computed from window coords.
__device__ __forceinline__ int regid(int t, int wh, int ww) {
  int i = t / 7;
  int j = t - i * 7;
  int rh = (wh == 7) ? ((i < 4) ? 1 : 2) : 0;
  int rw = (ww == 7) ? ((j < 4) ? 1 : 2) : 0;
  return rh * 3 + rw;
}

// Repack [K x NCOL] row-major fp32 weight into bf16 MFMA frag order; ctg<scale_below
// columns-groups get *scale (used to fold SCALE*log2e into q-weights).
__global__ void repack_w(const float* __restrict__ w, ushort* __restrict__ packed,
                         int ncol, int scale_below, float scale) {
  int ctg  = blockIdx.x;
  int kt   = threadIdx.x >> 6;
  int lane = threadIdx.x & 63;
  int col  = ctg * 16 + (lane & 15);
  int k0   = kt * 32 + (lane >> 4) * 8;
  float s  = (ctg < scale_below) ? scale : 1.0f;
  ushort* dst = packed + (size_t)((ctg * 4 + kt) * 64 + lane) * 8;
#pragma unroll
  for (int j = 0; j < 8; ++j) {
    __bf16 h = (__bf16)(w[(size_t)(k0 + j) * ncol + col] * s);
    dst[j] = __builtin_bit_cast(ushort, h);
  }
}

__global__ __launch_bounds__(256, 3)
void swin_fused(const float* __restrict__ x,
                const float* __restrict__ qkv_b,
                const float* __restrict__ proj_b,
                const ushort* __restrict__ pqkv,
                const ushort* __restrict__ pproj,
                float* __restrict__ out)
{
  __shared__ alignas(16) ushort ao[64 * 136];   // 17408 B, only cross-wave buffer

  const int wid = blockIdx.x;
  const int b   = wid >> 6;
  const int wh  = (wid >> 3) & 7;
  const int ww  = wid & 7;
  const int tid  = threadIdx.x;
  const int wave = tid >> 6;   // = head
  const int lane = tid & 63;
  const int c    = lane & 15;
  const int g    = lane >> 4;
  const int g0   = g & 1;
  const int g1   = g >> 1;
  const int addrA = (((2 * g0 + g1) << 4) | c) << 2;
  const int addrB = (((2 * (1 - g0) + g1) << 4) | c) << 2;
  const f32x4 zf = {0.f, 0.f, 0.f, 0.f};

  // ---- Phase 1: x fragments (idx=token=nt*16+c, kelem=dim) ----
  bf16x8 xf[4][4];
#pragma unroll
  for (int nt = 0; nt < 4; ++nt) {
    int token = nt * 16 + c;
    bool valid = token < NTOK;
    int tc = valid ? token : 0;
    int i = tc / 7;
    int j = tc - i * 7;
    int gh = wh * 7 + i + 3; if (gh >= 56) gh -= 56;
    int gw = ww * 7 + j + 3; if (gw >= 56) gw -= 56;
    const float* src = x + (((size_t)((b * 56 + gh) * 56 + gw)) << 7) + g * 8;
#pragma unroll
    for (int kt = 0; kt < 4; ++kt) {
      f32x4 lo = *reinterpret_cast<const f32x4*>(src + kt * 32);
      f32x4 hi = *reinterpret_cast<const f32x4*>(src + kt * 32 + 4);
      bf16x8 v = cvt8(lo, hi);
      xf[nt][kt] = valid ? v : bf16x8{};
    }
  }

  // ---- Phase 2: k^T, q^T, v GEMMs (3 passes to cap VGPR) ----
  unsigned int pkk[2][4][2], pkq[2][4][2], pkv[4][2][2];

#pragma unroll
  for (int o = 0; o < 2; ++o) {   // o=0: k, o=1: q  (transposed: C = [hd][tok])
    f32x4 qc[2][4];
#pragma unroll
    for (int mt = 0; mt < 2; ++mt)
#pragma unroll
      for (int nt = 0; nt < 4; ++nt) qc[mt][nt] = zf;
#pragma unroll
    for (int kt = 0; kt < 4; ++kt) {
      bf16x8 w0 = *reinterpret_cast<const bf16x8*>(
          pqkv + (size_t)((((o ? 0 : 8) + wave * 2 + 0) * 4 + kt) * 64 + lane) * 8);
      bf16x8 w1 = *reinterpret_cast<const bf16x8*>(
          pqkv + (size_t)((((o ? 0 : 8) + wave * 2 + 1) * 4 + kt) * 64 + lane) * 8);
#pragma unroll
      for (int nt = 0; nt < 4; ++nt) {
        qc[0][nt] = mfma_bf16(w0, xf[nt][kt], qc[0][nt]);
        qc[1][nt] = mfma_bf16(w1, xf[nt][kt], qc[1][nt]);
      }
    }
    float bscale = o ? QS : 1.0f;
    int bbase = (o ? 0 : 128) + wave * 32;
#pragma unroll
    for (int mt = 0; mt < 2; ++mt)
#pragma unroll
      for (int r = 0; r < 4; ++r) {
        float bv = qkv_b[bbase + mt * 16 + g * 4 + r] * bscale;
#pragma unroll
        for (int nt = 0; nt < 4; ++nt) qc[mt][nt][r] += bv;
      }
#pragma unroll
    for (int mt = 0; mt < 2; ++mt)
#pragma unroll
      for (int nt = 0; nt < 4; ++nt) {
        unsigned int* dst = o ? pkq[mt][nt] : pkk[mt][nt];
        dst[0] = pack2(qc[mt][nt][0], qc[mt][nt][1]);
        dst[1] = pack2(qc[mt][nt][2], qc[mt][nt][3]);
      }
  }

  {  // v (normal orientation: C = [tok][hd])
    f32x4 vc[4][2];
#pragma unroll
    for (int mt = 0; mt < 4; ++mt) { vc[mt][0] = zf; vc[mt][1] = zf; }
#pragma unroll
    for (int kt = 0; kt < 4; ++kt) {
      bf16x8 w0 = *reinterpret_cast<const bf16x8*>(
          pqkv + (size_t)(((16 + wave * 2 + 0) * 4 + kt) * 64 + lane) * 8);
      bf16x8 w1 = *reinterpret_cast<const bf16x8*>(
          pqkv + (size_t)(((16 + wave * 2 + 1) * 4 + kt) * 64 + lane) * 8);
#pragma unroll
      for (int mt = 0; mt < 4; ++mt) {
        vc[mt][0] = mfma_bf16(xf[mt][kt], w0, vc[mt][0]);
        vc[mt][1] = mfma_bf16(xf[mt][kt], w1, vc[mt][1]);
      }
    }
    float bv0 = qkv_b[256 + wave * 32 + c];
    float bv1 = qkv_b[256 + wave * 32 + 16 + c];
#pragma unroll
    for (int mt = 0; mt < 4; ++mt)
#pragma unroll
      for (int r = 0; r < 4; ++r) { vc[mt][0][r] += bv0; vc[mt][1][r] += bv1; }
#pragma unroll
    for (int mt = 0; mt < 4; ++mt)
#pragma unroll
      for (int nv = 0; nv < 2; ++nv) {
        pkv[mt][nv][0] = pack2(vc[mt][nv][0], vc[mt][nv][1]);
        pkv[mt][nv][1] = pack2(vc[mt][nv][2], vc[mt][nv][3]);
      }
  }

  // ---- Phase 3: S^T = mfma(k-frag, q-frag); frags via push-permute ----
  bf16x8 ka[4], qa[4];
#pragma unroll
  for (int t4 = 0; t4 < 4; ++t4) {
    ka[t4] = push_frag(pkk[0][t4][0], pkk[0][t4][1], pkk[1][t4][0], pkk[1][t4][1],
                       addrA, addrB, g0, g1);
    qa[t4] = push_frag(pkq[0][t4][0], pkq[0][t4][1], pkq[1][t4][0], pkq[1][t4][1],
                       addrA, addrB, g0, g1);
  }
  f32x4 st[4][4];
#pragma unroll
  for (int m = 0; m < 4; ++m)
#pragma unroll
    for (int n = 0; n < 4; ++n)
      st[m][n] = mfma_bf16(ka[m], qa[n], zf);

  // ---- Softmax over k (rows of S^T): per q-col, 16 in-lane + 2 shfl ----
  int ridq[4];
#pragma unroll
  for (int n = 0; n < 4; ++n) ridq[n] = regid(n * 16 + c, wh, ww);
  int ridk[4][4];
#pragma unroll
  for (int m = 0; m < 4; ++m)
#pragma unroll
    for (int r = 0; r < 4; ++r) {
      int kt_ = m * 16 + g * 4 + r;
      ridk[m][r] = (kt_ < NTOK) ? regid(kt_, wh, ww) : -1;
    }

  unsigned int pkp[4][4][2];
#pragma unroll
  for (int n = 0; n < 4; ++n) {
    float ev[4][4];
    float mx = -1e30f;
#pragma unroll
    for (int m = 0; m < 4; ++m)
#pragma unroll
      for (int r = 0; r < 4; ++r) {
        float v = (ridk[m][r] == ridq[n]) ? st[m][n][r] : -1e30f;
        ev[m][r] = v;
        mx = fmaxf(mx, v);
      }
    mx = fmaxf(mx, __shfl_xor(mx, 16));
    mx = fmaxf(mx, __shfl_xor(mx, 32));
    float sm = 0.f;
#pragma unroll
    for (int m = 0; m < 4; ++m)
#pragma unroll
      for (int r = 0; r < 4; ++r) {
        float e = exp2f(ev[m][r] - mx);   // scores already in log2e units
        ev[m][r] = e;
        sm += e;
      }
    sm += __shfl_xor(sm, 16);
    sm += __shfl_xor(sm, 32);
    float rinv = __fdividef(1.f, sm);
#pragma unroll
    for (int m = 0; m < 4; ++m) {
      pkp[m][n][0] = pack2(ev[m][0] * rinv, ev[m][1] * rinv);
      pkp[m][n][1] = pack2(ev[m][2] * rinv, ev[m][3] * rinv);
    }
  }

  // ---- PV: out = P @ V, frags chained from S^T-C and V-C ----
  f32x4 po[4][2];
#pragma unroll
  for (int m = 0; m < 4; ++m) { po[m][0] = zf; po[m][1] = zf; }
#pragma unroll
  for (int kt = 0; kt < 2; ++kt) {
    bf16x8 vf0 = push_frag(pkv[2 * kt][0][0], pkv[2 * kt][0][1],
                           pkv[2 * kt + 1][0][0], pkv[2 * kt + 1][0][1],
                           addrA, addrB, g0, g1);
    bf16x8 vf1 = push_frag(pkv[2 * kt][1][0], pkv[2 * kt][1][1],
                           pkv[2 * kt + 1][1][0], pkv[2 * kt + 1][1][1],
                           addrA, addrB, g0, g1);
#pragma unroll
    for (int m = 0; m < 4; ++m) {
      bf16x8 pa = push_frag(pkp[2 * kt][m][0], pkp[2 * kt][m][1],
                            pkp[2 * kt + 1][m][0], pkp[2 * kt + 1][m][1],
                            addrA, addrB, g0, g1);
      po[m][0] = mfma_bf16(pa, vf0, po[m][0]);
      po[m][1] = mfma_bf16(pa, vf1, po[m][1]);
    }
  }

  // ---- ao: [tok][dim] bf16, stride 136 shorts; the one cross-wave handoff ----
#pragma unroll
  for (int m = 0; m < 4; ++m)
#pragma unroll
    for (int nv = 0; nv < 2; ++nv)
#pragma unroll
      for (int r = 0; r < 4; ++r) {
        __bf16 h = (__bf16)po[m][nv][r];
        ao[(m * 16 + g * 4 + r) * 136 + wave * 32 + nv * 16 + c] =
            __builtin_bit_cast(ushort, h);
      }
  __syncthreads();

  // ---- Proj GEMM: wave computes out cols [wave*32, wave*32+32) ----
  f32x4 acc2[4][2];
#pragma unroll
  for (int m = 0; m < 4; ++m) { acc2[m][0] = zf; acc2[m][1] = zf; }
#pragma unroll
  for (int kt = 0; kt < 4; ++kt) {
    bf16x8 b20 = *reinterpret_cast<const bf16x8*>(
        pproj + (size_t)(((wave * 2 + 0) * 4 + kt) * 64 + lane) * 8);
    bf16x8 b21 = *reinterpret_cast<const bf16x8*>(
        pproj + (size_t)(((wave * 2 + 1) * 4 + kt) * 64 + lane) * 8);
#pragma unroll
    for (int m = 0; m < 4; ++m) {
      bf16x8 af = *reinterpret_cast<const bf16x8*>(&ao[(m * 16 + c) * 136 + kt * 32 + g * 8]);
      acc2[m][0] = mfma_bf16(af, b20, acc2[m][0]);
      acc2[m][1] = mfma_bf16(af, b21, acc2[m][1]);
    }
  }
  float pb0 = proj_b[wave * 32 + c];
  float pb1 = proj_b[wave * 32 + 16 + c];

  // ---- Epilogue: reverse roll, fp32 stores ----
#pragma unroll
  for (int m = 0; m < 4; ++m)
#pragma unroll
    for (int r = 0; r < 4; ++r) {
      int token = m * 16 + g * 4 + r;
      if (token < NTOK) {
        int i = token / 7;
        int j = token - i * 7;
        int oh = wh * 7 + i + 3; if (oh >= 56) oh -= 56;
        int ow = ww * 7 + j + 3; if (ow >= 56) ow -= 56;
        float* dst = out + (((size_t)((b * 56 + oh) * 56 + ow)) << 7) + wave * 32;
        dst[c]      = acc2[m][0][r] + pb0;
        dst[16 + c] = acc2[m][1][r] + pb1;
      }
    }
}

extern "C" void kernel_launch(void* const* d_in, const int* in_sizes, int n_in,
                              void* d_out, int out_size, void* d_ws, size_t ws_size,
                              hipStream_t stream) {
  const float* x      = (const float*)d_in[0];
  const float* qkv_w  = (const float*)d_in[1];
  const float* qkv_b  = (const float*)d_in[2];
  const float* proj_w = (const float*)d_in[3];
  const float* proj_b = (const float*)d_in[4];
  float* out = (float*)d_out;

  ushort* pqkv  = (ushort*)d_ws;            // 24*4*64*8 = 49152 shorts (96 KiB)
  ushort* pproj = pqkv + 49152;             //  8*4*64*8 = 16384 shorts (32 KiB)

  repack_w<<<24, 256, 0, stream>>>(qkv_w, pqkv, 384, 8, QS);   // scale q-cols
  repack_w<<<8, 256, 0, stream>>>(proj_w, pproj, 128, 0, 1.0f);
  swin_fused<<<4096, 256, 0, stream>>>(x, qkv_b, proj_b, pqkv, pproj, out);
}